// Round 1
// baseline (482.610 us; speedup 1.0000x reference)
//
#include <hip/hip_runtime.h>
#include <math.h>

#define Nn 8192
#define Dd 256
#define NBINS 64
#define NSPLIT 8

// ---------------- K0: row squared norms + init pos/neg accumulators ----------------
__global__ __launch_bounds__(256) void prep_kernel(const float* __restrict__ x,
                                                   float* __restrict__ sq,
                                                   int* __restrict__ pos2,
                                                   int* __restrict__ neg2) {
  const int w = threadIdx.x >> 6;
  const int lane = threadIdx.x & 63;
  const int row = blockIdx.x * 4 + w;
  const float4 v = *(const float4*)(x + (size_t)row * Dd + lane * 4);
  float s = v.x * v.x + v.y * v.y + v.z * v.z + v.w * v.w;
#pragma unroll
  for (int off = 32; off >= 1; off >>= 1) s += __shfl_xor(s, off);
  if (lane == 0) {
    sq[row] = s;
    pos2[row] = 0;           // 0.0f  (dist^2 >= 1e-12 > 0, safe identity for max)
    neg2[row] = 0x7f800000;  // +inf  (safe identity for min)
  }
}

// ---------------- K1: fused pairwise dist^2 + label-masked max/min ----------------
// 128x128 tile per block iteration, 8x8 per-thread register blocking,
// K staged in LDS transposed [k][row] with pad 132 (16B-aligned float4 rows).
__global__ __launch_bounds__(256) void pairwise_kernel(const float* __restrict__ x,
                                                       const int* __restrict__ lab,
                                                       const float* __restrict__ sq,
                                                       int* __restrict__ pos2,
                                                       int* __restrict__ neg2) {
  __shared__ float a_s[32][132];
  __shared__ float b_s[32][132];
  const int t = threadIdx.x;
  const int tx = t & 15, ty = t >> 4;
  const int rows0 = blockIdx.x * 128;
  const int c_begin = blockIdx.y * (Nn / NSPLIT);
  const int c_end = c_begin + (Nn / NSPLIT);

  float sqr[8]; int labr[8];
#pragma unroll
  for (int r = 0; r < 4; ++r) {
    sqr[r]     = sq[rows0 + 4 * ty + r];       labr[r]     = lab[rows0 + 4 * ty + r];
    sqr[4 + r] = sq[rows0 + 64 + 4 * ty + r];  labr[4 + r] = lab[rows0 + 64 + 4 * ty + r];
  }
  float posd[8], negd[8];
#pragma unroll
  for (int r = 0; r < 8; ++r) { posd[r] = 0.0f; negd[r] = INFINITY; }

  for (int c0 = c_begin; c0 < c_end; c0 += 128) {
    float acc[8][8];
#pragma unroll
    for (int r = 0; r < 8; ++r)
#pragma unroll
      for (int c = 0; c < 8; ++c) acc[r][c] = 0.0f;

    for (int kc = 0; kc < Dd; kc += 32) {
      __syncthreads();
#pragma unroll
      for (int i = 0; i < 4; ++i) {
        const int idx = t + i * 256;
        const int row = idx >> 3;         // 0..127
        const int k = (idx & 7) << 2;     // 0,4,...,28
        const float4 va = *(const float4*)(x + (size_t)(rows0 + row) * Dd + kc + k);
        const float4 vb = *(const float4*)(x + (size_t)(c0 + row) * Dd + kc + k);
        a_s[k + 0][row] = va.x; a_s[k + 1][row] = va.y; a_s[k + 2][row] = va.z; a_s[k + 3][row] = va.w;
        b_s[k + 0][row] = vb.x; b_s[k + 1][row] = vb.y; b_s[k + 2][row] = vb.z; b_s[k + 3][row] = vb.w;
      }
      __syncthreads();
#pragma unroll 8
      for (int k = 0; k < 32; ++k) {
        const float4 a0 = *(const float4*)&a_s[k][4 * ty];
        const float4 a1 = *(const float4*)&a_s[k][64 + 4 * ty];
        const float4 b0 = *(const float4*)&b_s[k][4 * tx];
        const float4 b1 = *(const float4*)&b_s[k][64 + 4 * tx];
        const float ar[8] = {a0.x, a0.y, a0.z, a0.w, a1.x, a1.y, a1.z, a1.w};
        const float bc[8] = {b0.x, b0.y, b0.z, b0.w, b1.x, b1.y, b1.z, b1.w};
#pragma unroll
        for (int r = 0; r < 8; ++r)
#pragma unroll
          for (int c = 0; c < 8; ++c)
            acc[r][c] = fmaf(ar[r], bc[c], acc[r][c]);
      }
    }
    // epilogue: dist^2 + masked reductions (monotone: reduce on dist^2, sqrt later)
    float sqc[8]; int labc[8];
#pragma unroll
    for (int c = 0; c < 4; ++c) {
      sqc[c]     = sq[c0 + 4 * tx + c];       labc[c]     = lab[c0 + 4 * tx + c];
      sqc[4 + c] = sq[c0 + 64 + 4 * tx + c];  labc[4 + c] = lab[c0 + 64 + 4 * tx + c];
    }
#pragma unroll
    for (int r = 0; r < 8; ++r) {
#pragma unroll
      for (int c = 0; c < 8; ++c) {
        float d2 = fmaxf(sqr[r] + sqc[c] - 2.0f * acc[r][c], 1e-12f);
        if (labr[r] == labc[c]) posd[r] = fmaxf(posd[r], d2);
        else                    negd[r] = fminf(negd[r], d2);
      }
    }
  }
  // merge across the 16 tx lanes (same rows), then one atomic per row
#pragma unroll
  for (int r = 0; r < 8; ++r) {
    float p = posd[r], nn = negd[r];
#pragma unroll
    for (int off = 1; off < 16; off <<= 1) {
      p = fmaxf(p, __shfl_xor(p, off));
      nn = fminf(nn, __shfl_xor(nn, off));
    }
    if (tx == 0) {
      const int row = (r < 4) ? (rows0 + 4 * ty + r) : (rows0 + 64 + 4 * ty + (r - 4));
      atomicMax(&pos2[row], __float_as_int(p));
      atomicMin(&neg2[row], __float_as_int(nn));
    }
  }
}

// ---------------- K2: finalize (single block): hv, extremes, histogram, cdf, loss ----------------
__global__ __launch_bounds__(1024) void finalize_kernel(const int* __restrict__ pos2,
                                                        const int* __restrict__ neg2,
                                                        float* __restrict__ out) {
  __shared__ float hv_s[Nn];
  __shared__ float rbuf[16];
  __shared__ float rbuf2[16];
  __shared__ float hist_s[NBINS];
  __shared__ float cdf_s[NBINS];
  __shared__ float s_minv, s_bw;
  const int t = threadIdx.x;
  const int lane = t & 63, wid = t >> 6;

  float lmax = -INFINITY, lmin = INFINITY;
  for (int i = t; i < Nn; i += 1024) {
    const float p = sqrtf(__int_as_float(pos2[i]));
    const float nn = sqrtf(__int_as_float(neg2[i]));
    const float hv = p - nn;
    hv_s[i] = hv;
    lmax = fmaxf(lmax, hv);
    lmin = fminf(lmin, hv);
  }
#pragma unroll
  for (int off = 32; off >= 1; off >>= 1) {
    lmax = fmaxf(lmax, __shfl_xor(lmax, off));
    lmin = fminf(lmin, __shfl_xor(lmin, off));
  }
  if (lane == 0) { rbuf[wid] = lmax; rbuf2[wid] = lmin; }
  __syncthreads();
  if (t == 0) {
    float gmax = rbuf[0], gmin = rbuf2[0];
    for (int w = 1; w < 16; ++w) { gmax = fmaxf(gmax, rbuf[w]); gmin = fminf(gmin, rbuf2[w]); }
    const float maxv = fmaxf(gmax, 2.0f);
    const float minv = fminf(gmin, -2.0f);
    s_minv = minv;
    s_bw = (maxv - minv) / (float)(NBINS - 1);
  }
  if (t < NBINS) hist_s[t] = 0.0f;
  __syncthreads();

  const float minv = s_minv, bw = s_bw;
  for (int i = t; i < Nn; i += 1024) {
    const float hv = hv_s[i];
    int lo = (int)floorf((hv - minv) / bw);
    lo = min(max(lo, 0), NBINS - 1);
    const int hi = min(lo + 1, NBINS - 1);
    const float alpha = 1.0f - (hv - minv - (float)lo * bw) / bw;
    atomicAdd(&hist_s[lo], alpha);
    atomicAdd(&hist_s[hi], 1.0f - alpha);
  }
  __syncthreads();

  if (t < NBINS) {
    const float h = hist_s[t];
    float total = h;
#pragma unroll
    for (int off = 32; off >= 1; off >>= 1) total += __shfl_xor(total, off);
    const float hn = h / (total + 1e-6f);
    float s2 = hn;
#pragma unroll
    for (int off = 32; off >= 1; off >>= 1) s2 += __shfl_xor(s2, off);
    const float pdf = hn / s2;
    float c = pdf;
#pragma unroll
    for (int off = 1; off < 64; off <<= 1) {
      const float u = __shfl_up(c, off);
      if (lane >= off) c += u;
    }
    cdf_s[t] = c;
  }
  __syncthreads();

  float acc = 0.0f;
  for (int i = t; i < Nn; i += 1024) {
    const float hv = hv_s[i];
    int lo = (int)floorf((hv - minv) / bw);
    lo = min(max(lo, 0), NBINS - 1);
    acc += cdf_s[lo] * hv;
  }
#pragma unroll
  for (int off = 32; off >= 1; off >>= 1) acc += __shfl_xor(acc, off);
  if (lane == 0) rbuf[wid] = acc;
  __syncthreads();
  if (t == 0) {
    float s = 0.0f;
    for (int w = 0; w < 16; ++w) s += rbuf[w];
    out[0] = s / (float)Nn;
  }
}

// ---------------- launch ----------------
extern "C" void kernel_launch(void* const* d_in, const int* in_sizes, int n_in,
                              void* d_out, int out_size, void* d_ws, size_t ws_size,
                              hipStream_t stream) {
  const float* x = (const float*)d_in[0];
  const int* targets = (const int*)d_in[1];
  // d_in[2] (histogram buffer) is unused: first call has momentum = 1.0
  float* out = (float*)d_out;

  float* sq = (float*)d_ws;
  int* pos2 = (int*)((char*)d_ws + (size_t)Nn * sizeof(float));
  int* neg2 = (int*)((char*)d_ws + 2 * (size_t)Nn * sizeof(float));

  prep_kernel<<<Nn / 4, 256, 0, stream>>>(x, sq, pos2, neg2);
  pairwise_kernel<<<dim3(Nn / 128, NSPLIT), 256, 0, stream>>>(x, targets, sq, pos2, neg2);
  finalize_kernel<<<1, 1024, 0, stream>>>(pos2, neg2, out);
}

// Round 2
// 104.968 us; speedup vs baseline: 4.5977x; 4.5977x over previous
//
#include <hip/hip_runtime.h>
#include <math.h>

#define Nn 8192
#define Dd 256
#define NBINS 64
#define NSPLIT 8

typedef __attribute__((ext_vector_type(8))) short short8;
typedef __attribute__((ext_vector_type(4))) float f32x4;

#define GLOAD16(g, l)                                                        \
  __builtin_amdgcn_global_load_lds(                                          \
      (const __attribute__((address_space(1))) void*)(g),                    \
      (__attribute__((address_space(3))) void*)(l), 16, 0, 0)

static __device__ __forceinline__ unsigned short f2bf(float f) {
  unsigned int u = __float_as_uint(f);
  u = (u + 0x7fffu + ((u >> 16) & 1u)) >> 16;  // RNE
  return (unsigned short)u;
}

// ---------------- K0: bf16 cast + row squared norms (fp32) + init accumulators ----------------
__global__ __launch_bounds__(256) void prep_kernel(const float* __restrict__ x,
                                                   unsigned short* __restrict__ xb,
                                                   float* __restrict__ sq,
                                                   int* __restrict__ pos2,
                                                   int* __restrict__ neg2) {
  const int w = threadIdx.x >> 6;
  const int lane = threadIdx.x & 63;
  const int row = blockIdx.x * 4 + w;
  const float4 v = *(const float4*)(x + (size_t)row * Dd + lane * 4);
  ushort4 b;
  b.x = f2bf(v.x); b.y = f2bf(v.y); b.z = f2bf(v.z); b.w = f2bf(v.w);
  *(ushort4*)(xb + (size_t)row * Dd + lane * 4) = b;
  float s = v.x * v.x + v.y * v.y + v.z * v.z + v.w * v.w;
#pragma unroll
  for (int off = 32; off >= 1; off >>= 1) s += __shfl_xor(s, off);
  if (lane == 0) {
    sq[row] = s;
    pos2[row] = 0;           // 0.0f — true max dist^2 is always > 0
    neg2[row] = 0x7f800000;  // +inf
  }
}

// ---------------- K1: MFMA Gram tile + fused masked max/min ----------------
// Block: 128 rows x full K resident in LDS (A, 64KB, [kq][row] 16B-chunk layout).
// Loops over 8 col-tiles of 128; per K-step stages B (8KB) via global_load_lds.
// Epilogue keeps per-row running max/min of g = sqc - 2*acc (sqr added at end).
__global__ __launch_bounds__(256, 2) void pairwise_kernel(const unsigned short* __restrict__ xb,
                                                          const int* __restrict__ lab,
                                                          const float* __restrict__ sq,
                                                          int* __restrict__ pos2,
                                                          int* __restrict__ neg2) {
  __shared__ __align__(16) unsigned short As[Dd / 8 * 128 * 8];  // 32 kq x 128 rows x 8 elem = 64KB
  __shared__ __align__(16) unsigned short Bs[4 * 128 * 8];       // 4 kq x 128 cols x 8 elem = 8KB

  const int t = threadIdx.x;
  const int lane = t & 63;
  const int w = t >> 6;
  const int wr = w >> 1, wc = w & 1;
  const int c_l = lane & 15;   // fragment col (A row / B col)
  const int kq_l = lane >> 4;  // fragment k-octet
  const int rows0 = blockIdx.x * 128;
  const int cbase = blockIdx.y * (Nn / NSPLIT);

  // ---- stage A (full K) : linear LDS, [kq][row] chunk order ----
#pragma unroll
  for (int i = 0; i < 16; ++i) {
    const int s = i * 256 + t;            // 16B chunk index, 0..4095
    const int row = s & 127;
    const int kq = s >> 7;                // 0..31
    GLOAD16(xb + (size_t)(rows0 + row) * Dd + kq * 8, As + (size_t)s * 8);
  }

  // ---- per-row labels (16 rows per lane) ----
  int lab16[16];
#pragma unroll
  for (int m = 0; m < 4; ++m)
#pragma unroll
    for (int q = 0; q < 4; ++q)
      lab16[m * 4 + q] = lab[rows0 + wr * 64 + m * 16 + kq_l * 4 + q];

  float pmax[16], nmin[16];
#pragma unroll
  for (int i = 0; i < 16; ++i) { pmax[i] = -INFINITY; nmin[i] = INFINITY; }

  const short8* Av = (const short8*)As;
  const short8* Bv = (const short8*)Bs;

  for (int ct = 0; ct < (Nn / NSPLIT) / 128; ++ct) {
    const int c0 = cbase + ct * 128;
    f32x4 acc[4][4];
#pragma unroll
    for (int m = 0; m < 4; ++m)
#pragma unroll
      for (int n = 0; n < 4; ++n) acc[m][n] = (f32x4){0.f, 0.f, 0.f, 0.f};

    for (int ks = 0; ks < Dd / 32; ++ks) {
      __syncthreads();  // previous Bs reads done
#pragma unroll
      for (int i = 0; i < 2; ++i) {
        const int s = i * 256 + t;        // chunk 0..511
        const int col = s & 127;
        const int kq = s >> 7;            // 0..3
        GLOAD16(xb + (size_t)(c0 + col) * Dd + ks * 32 + kq * 8, Bs + (size_t)s * 8);
      }
      __syncthreads();  // Bs (and on first pass, As) ready

      short8 af[4], bf[4];
#pragma unroll
      for (int m = 0; m < 4; ++m)
        af[m] = Av[(ks * 4 + kq_l) * 128 + wr * 64 + m * 16 + c_l];
#pragma unroll
      for (int n = 0; n < 4; ++n)
        bf[n] = Bv[kq_l * 128 + wc * 64 + n * 16 + c_l];
#pragma unroll
      for (int m = 0; m < 4; ++m)
#pragma unroll
        for (int n = 0; n < 4; ++n)
          acc[m][n] = __builtin_amdgcn_mfma_f32_16x16x32_bf16(af[m], bf[n], acc[m][n], 0, 0, 0);
    }

    // ---- epilogue: masked running max/min on g = sqc - 2*acc ----
#pragma unroll
    for (int n = 0; n < 4; ++n) {
      const int colg = c0 + wc * 64 + n * 16 + c_l;
      const float sc = sq[colg];
      const int lc = lab[colg];
#pragma unroll
      for (int m = 0; m < 4; ++m)
#pragma unroll
        for (int q = 0; q < 4; ++q) {
          const float gg = fmaf(-2.0f, acc[m][n][q], sc);
          if (lab16[m * 4 + q] == lc) pmax[m * 4 + q] = fmaxf(pmax[m * 4 + q], gg);
          else                        nmin[m * 4 + q] = fminf(nmin[m * 4 + q], gg);
        }
    }
  }

  // ---- reduce over the 16 col-lanes, then atomics (2 per row per block) ----
#pragma unroll
  for (int i = 0; i < 16; ++i) {
    float p = pmax[i], nn = nmin[i];
#pragma unroll
    for (int off = 1; off < 16; off <<= 1) {
      p = fmaxf(p, __shfl_xor(p, off));
      nn = fminf(nn, __shfl_xor(nn, off));
    }
    if (c_l == 0) {
      const int rowg = rows0 + wr * 64 + (i >> 2) * 16 + kq_l * 4 + (i & 3);
      const float sr = sq[rowg];
      atomicMax(&pos2[rowg], __float_as_int(sr + p));
      atomicMin(&neg2[rowg], __float_as_int(sr + nn));
    }
  }
}

// ---------------- K2: finalize (single block): hv, extremes, histogram, cdf, loss ----------------
__global__ __launch_bounds__(1024) void finalize_kernel(const int* __restrict__ pos2,
                                                        const int* __restrict__ neg2,
                                                        float* __restrict__ out) {
  __shared__ float hv_s[Nn];
  __shared__ float rbuf[16];
  __shared__ float rbuf2[16];
  __shared__ float hist_s[NBINS];
  __shared__ float cdf_s[NBINS];
  __shared__ float s_minv, s_bw;
  const int t = threadIdx.x;
  const int lane = t & 63, wid = t >> 6;

  float lmax = -INFINITY, lmin = INFINITY;
  for (int i = t; i < Nn; i += 1024) {
    const float p = sqrtf(fmaxf(__int_as_float(pos2[i]), 0.0f));
    const float nn = sqrtf(__int_as_float(neg2[i]));
    const float hv = p - nn;
    hv_s[i] = hv;
    lmax = fmaxf(lmax, hv);
    lmin = fminf(lmin, hv);
  }
#pragma unroll
  for (int off = 32; off >= 1; off >>= 1) {
    lmax = fmaxf(lmax, __shfl_xor(lmax, off));
    lmin = fminf(lmin, __shfl_xor(lmin, off));
  }
  if (lane == 0) { rbuf[wid] = lmax; rbuf2[wid] = lmin; }
  __syncthreads();
  if (t == 0) {
    float gmax = rbuf[0], gmin = rbuf2[0];
    for (int w = 1; w < 16; ++w) { gmax = fmaxf(gmax, rbuf[w]); gmin = fminf(gmin, rbuf2[w]); }
    const float maxv = fmaxf(gmax, 2.0f);
    const float minv = fminf(gmin, -2.0f);
    s_minv = minv;
    s_bw = (maxv - minv) / (float)(NBINS - 1);
  }
  if (t < NBINS) hist_s[t] = 0.0f;
  __syncthreads();

  const float minv = s_minv, bw = s_bw;
  for (int i = t; i < Nn; i += 1024) {
    const float hv = hv_s[i];
    int lo = (int)floorf((hv - minv) / bw);
    lo = min(max(lo, 0), NBINS - 1);
    const int hi = min(lo + 1, NBINS - 1);
    const float alpha = 1.0f - (hv - minv - (float)lo * bw) / bw;
    atomicAdd(&hist_s[lo], alpha);
    atomicAdd(&hist_s[hi], 1.0f - alpha);
  }
  __syncthreads();

  if (t < NBINS) {
    const float h = hist_s[t];
    float total = h;
#pragma unroll
    for (int off = 32; off >= 1; off >>= 1) total += __shfl_xor(total, off);
    const float hn = h / (total + 1e-6f);
    float s2 = hn;
#pragma unroll
    for (int off = 32; off >= 1; off >>= 1) s2 += __shfl_xor(s2, off);
    const float pdf = hn / s2;
    float c = pdf;
#pragma unroll
    for (int off = 1; off < 64; off <<= 1) {
      const float u = __shfl_up(c, off);
      if (lane >= off) c += u;
    }
    cdf_s[t] = c;
  }
  __syncthreads();

  float acc = 0.0f;
  for (int i = t; i < Nn; i += 1024) {
    const float hv = hv_s[i];
    int lo = (int)floorf((hv - minv) / bw);
    lo = min(max(lo, 0), NBINS - 1);
    acc += cdf_s[lo] * hv;
  }
#pragma unroll
  for (int off = 32; off >= 1; off >>= 1) acc += __shfl_xor(acc, off);
  if (lane == 0) rbuf[wid] = acc;
  __syncthreads();
  if (t == 0) {
    float s = 0.0f;
    for (int w = 0; w < 16; ++w) s += rbuf[w];
    out[0] = s / (float)Nn;
  }
}

// ---------------- launch ----------------
extern "C" void kernel_launch(void* const* d_in, const int* in_sizes, int n_in,
                              void* d_out, int out_size, void* d_ws, size_t ws_size,
                              hipStream_t stream) {
  const float* x = (const float*)d_in[0];
  const int* targets = (const int*)d_in[1];
  float* out = (float*)d_out;

  unsigned short* xb = (unsigned short*)d_ws;                       // 4 MB
  char* p = (char*)d_ws + (size_t)Nn * Dd * sizeof(unsigned short);
  float* sq = (float*)p;
  int* pos2 = (int*)(p + (size_t)Nn * sizeof(float));
  int* neg2 = (int*)(p + 2 * (size_t)Nn * sizeof(float));

  prep_kernel<<<Nn / 4, 256, 0, stream>>>(x, xb, sq, pos2, neg2);
  pairwise_kernel<<<dim3(Nn / 128, NSPLIT), 256, 0, stream>>>(xb, targets, sq, pos2, neg2);
  finalize_kernel<<<1, 1024, 0, stream>>>(pos2, neg2, out);
}